// Round 11
// baseline (146.707 us; speedup 1.0000x reference)
//
#include <hip/hip_runtime.h>

typedef _Float16 f16;
typedef f16 f16x2 __attribute__((ext_vector_type(2)));
typedef f16 f16x8 __attribute__((ext_vector_type(8)));
typedef float f32x4 __attribute__((ext_vector_type(4)));
typedef float f32x16 __attribute__((ext_vector_type(16)));
typedef unsigned int u32;
typedef u32 u32x2 __attribute__((ext_vector_type(2)));
typedef u32 u32x4 __attribute__((ext_vector_type(4)));

#define B_TOTAL 262144
#define NBLK    512
#define TPW     2      // 32-sample tiles per wave; 512 blk * 8 waves * 2 * 32 = 262144

// ---- ws / LDS layout (u32 indices) ----
#define OFF_QP   0       // Q frags:  [4 mt][8 kk][64 lane][4 u32] = 8192
#define OFF_M2P  8192    // M2 frags: same = 8192
#define OFF_W1H  16384   // W1 (rows j=lane&31, zero j>=7): [8 kk][64 lane][4 u32] = 2048
#define OFF_W1ZT 18432   // W1z A-frags: [4 mt][64 lane][2 u32] = 512 (j pairs; j==7 -> b1)
#define OFF_W2B  18944   // w2b = W2*b2: f32[128]
#define IDX_C2   19072   // ||b2||^2
#define NW_U32   19076   // = 4769 u32x4

static __device__ inline u32 pkrtz(float a, float b) {
  auto r = __builtin_amdgcn_cvt_pkrtz(a, b);
  return __builtin_bit_cast(u32, r);
}
static __device__ inline float lo16f(u32 x) { f16x2 h = __builtin_bit_cast(f16x2, x); return (float)h[0]; }
static __device__ inline float hi16f(u32 x) { f16x2 h = __builtin_bit_cast(f16x2, x); return (float)h[1]; }
static __device__ inline f16x8 frag4(const u32 v[4]) {
  u32x4 t = { v[0], v[1], v[2], v[3] };
  return __builtin_bit_cast(f16x8, t);
}
static __device__ inline f16x8 fragv(u32x4 v) { return __builtin_bit_cast(f16x8, v); }
static __device__ inline f32x16 mfma32(f16x8 a, f16x8 b, f32x16 c) {
  return __builtin_amdgcn_mfma_f32_32x32x16_f16(a, b, c, 0, 0, 0);
}
static __device__ inline float fdot2f(u32 a, u32 b, float c) {
  return __builtin_amdgcn_fdot2(__builtin_bit_cast(f16x2, a),
                                __builtin_bit_cast(f16x2, b), c, false);
}
// s = 1 - t^2 as one packed v_pk_fma_f16 (rematerializable; no persistent sf_ array)
static __device__ inline u32 s_from_t(u32 t) {
  f16x2 tv = __builtin_bit_cast(f16x2, t);
  f16x2 one = { (f16)1.0f, (f16)1.0f };
  f16x2 sv = __builtin_elementwise_fma(-tv, tv, one);
  return __builtin_bit_cast(u32, sv);
}
static __device__ inline u32 pkmul(u32 a, u32 b) {
  f16x2 r = __builtin_bit_cast(f16x2, a) * __builtin_bit_cast(f16x2, b);
  return __builtin_bit_cast(u32, r);
}
// k-slot convention (validated by rounds 4/5/10 passing): slot w (0..7), half g ->
// klocal = (w&3) + 8*(w>>2) + 4g  (K=16)
static __device__ __host__ inline int kl(int w, int g) { return (w & 3) + 8 * (w >> 2) + 4 * g; }

// Jacobi fallback (only if a GE pivot is tiny -- never for this data distribution)
__device__ __noinline__ void eig7_fallback(const float* Mg, float* det_o, float* lpos_o) {
  float a[49];
  for (int i = 0; i < 49; ++i) a[i] = Mg[i];
  for (int sw = 0; sw < 10; ++sw)
    for (int p = 0; p < 6; ++p)
      for (int q = p + 1; q < 7; ++q) {
        float apq = a[p*7+q];
        if (fabsf(apq) < 1e-12f) continue;
        float th = 0.5f*(a[q*7+q] - a[p*7+p]) / apq;
        float tt = 1.0f/(fabsf(th) + sqrtf(th*th + 1.0f));
        if (th < 0.0f) tt = -tt;
        float cc = 1.0f/sqrtf(tt*tt + 1.0f), ss = tt*cc;
        for (int i = 0; i < 7; ++i) {
          float aip = a[i*7+p], aiq = a[i*7+q];
          a[i*7+p] = cc*aip - ss*aiq; a[i*7+q] = ss*aip + cc*aiq;
        }
        for (int i = 0; i < 7; ++i) {
          float api = a[p*7+i], aqi = a[q*7+i];
          a[p*7+i] = cc*api - ss*aqi; a[q*7+i] = ss*api + cc*aqi;
        }
      }
  float det = 1.0f, lp = 0.0f;
  for (int i = 0; i < 7; ++i) {
    float e = a[i*7+i];
    det *= e;
    float rl = fmaxf(1e-6f - e, 0.0f);
    lp += rl*rl;
  }
  *det_o = det; *lpos_o = lp * (1.0f/7.0f);
}

__global__ void g2_prep(const float* __restrict__ W1, const float* __restrict__ b1,
                        const float* __restrict__ W2, const float* __restrict__ b2,
                        u32* __restrict__ ws) {
  int gid = blockIdx.x * 256 + threadIdx.x;
  if (gid < 8192) {                         // QP + M2P frags (lane-contiguous)
    int frag = gid >> 8;                    // mt*8 + kk
    int lane = (gid >> 2) & 63, w2 = gid & 3;
    int mt = frag >> 3, kk = frag & 7;
    int g = lane >> 5, row = 32*mt + (lane & 31);
    int k0 = 16*kk + kl(2*w2,     g);
    int k1 = 16*kk + kl(2*w2 + 1, g);
    float m2a = 0.f, m2b = 0.f;
    for (int x = 0; x < 35; ++x) {
      float wh = W2[row*35 + x];
      m2a = fmaf(wh, W2[k0*35 + x], m2a);
      m2b = fmaf(wh, W2[k1*35 + x], m2b);
    }
    float n1a = 0.f, n1b = 0.f;
    for (int j = 0; j < 7; ++j) {
      float wj = W1[j*128 + row];
      n1a = fmaf(wj, W1[j*128 + k0], n1a);
      n1b = fmaf(wj, W1[j*128 + k1], n1b);
    }
    ws[OFF_QP  + gid] = pkrtz(m2a*n1a, m2b*n1b);
    ws[OFF_M2P + gid] = pkrtz(m2a, m2b);
  } else if (gid < 10240) {                 // W1H frags: A rows j = lane&31 (>=7 zero)
    int idx = gid - 8192;
    int kk = idx >> 8, lane = (idx >> 2) & 63, w2 = idx & 3;
    int g = lane >> 5, j = lane & 31;
    float a = 0.f, b = 0.f;
    if (j < 7) {
      a = W1[j*128 + 16*kk + kl(2*w2,     g)];
      b = W1[j*128 + 16*kk + kl(2*w2 + 1, g)];
    }
    ws[OFF_W1H + idx] = pkrtz(a, b);
  } else if (gid < 10752) {                 // W1zT frags: rows h, k slots j (j==7 -> b1)
    int idx = gid - 10240;
    int mt = idx >> 7, r = idx & 127, lane = r >> 1, half = r & 1;
    int g = lane >> 5, h = 32*mt + (lane & 31);
    int j0 = 4*g + 2*half, j1 = j0 + 1;     // j0 in {0,2,4,6}
    float a = W1[j0*128 + h];
    float b = (j1 < 7) ? W1[j1*128 + h] : b1[h];
    ws[OFF_W1ZT + mt*128 + lane*2 + half] = pkrtz(a, b);
  } else if (gid < 10880) {                 // w2b = W2 b2
    int h = gid - 10752;
    float s = 0.f;
    for (int x = 0; x < 35; ++x) s = fmaf(W2[h*35 + x], b2[x], s);
    ws[OFF_W2B + h] = __builtin_bit_cast(u32, s);
  } else if (gid == 10880) {                // c2 = ||b2||^2
    float s = 0.f;
    for (int x = 0; x < 35; ++x) s = fmaf(b2[x], b2[x], s);
    ws[IDX_C2] = __builtin_bit_cast(u32, s);
  }
}

__global__ __launch_bounds__(512, 2) void g2_main(
    const float* __restrict__ coords, const float* __restrict__ metric,
    const u32* __restrict__ wsW, float* __restrict__ partials) {
  __shared__ __align__(16) u32 SMEM[NW_U32];
  const int tid = threadIdx.x;

  { // stage weights: 4769 uint4
    const u32x4* src = (const u32x4*)wsW;
    u32x4* dst = (u32x4*)SMEM;
    #pragma unroll
    for (int i = 0; i < 10; ++i) {
      int idx = tid + 512 * i;
      if (idx < 4769) dst[idx] = src[idx];
    }
  }
  __syncthreads();

  const int lane = tid & 63, wv = tid >> 6;
  const int g = lane >> 5, cs = lane & 31;
  const int wave_gid = blockIdx.x * 8 + wv;
  const int sbase = wave_gid * 64;
  const char* LB = (const char*)SMEM;
  const float c2v = ((const float*)SMEM)[IDX_C2];

  // ---- dets for both tiles up-front (symmetric GE on lower triangle) ----
  float detv = 1.f, lposv = 0.f;
  {
    const float* Mg = metric + (size_t)(sbase + lane) * 49;
    float m[28];
    #pragma unroll
    for (int i = 0; i < 7; ++i)
      #pragma unroll
      for (int j = 0; j <= i; ++j)
        m[i*(i+1)/2 + j] = Mg[i*7 + j];
    float minpiv = 3.4e38f;
    #pragma unroll
    for (int k = 0; k < 7; ++k) {
      float piv = m[k*(k+1)/2 + k];
      minpiv = fminf(minpiv, piv);
      detv *= piv;
      float inv = 1.0f / piv;
      #pragma unroll
      for (int i = k + 1; i < 7; ++i) {
        float f = m[i*(i+1)/2 + k] * inv;
        #pragma unroll
        for (int j = k + 1; j <= i; ++j)
          m[i*(i+1)/2 + j] = fmaf(-f, m[j*(j+1)/2 + k], m[i*(i+1)/2 + j]);
      }
    }
    if (!(minpiv > 1e-4f)) eig7_fallback(Mg, &detv, &lposv);
  }

  float acc = 0.f;

  #pragma unroll 1
  for (int t = 0; t < TPW; ++t) {
    // ---- phase 1: Z = W1z^T C via MFMA; tanh -> tf_ only (lane-local) ----
    const float* cg = coords + (size_t)(sbase + 32*t + cs) * 7;
    u32 bcv[4] = {0,0,0,0};
    if (g == 0) { bcv[0] = pkrtz(cg[0], cg[1]); bcv[1] = pkrtz(cg[2], cg[3]); }
    else        { bcv[0] = pkrtz(cg[4], cg[5]); bcv[1] = pkrtz(cg[6], 1.0f); }
    const f16x8 bfrag = frag4(bcv);

    u32 tf_[8][4];
    float w2t = 0.f;
    #pragma unroll
    for (int mt = 0; mt < 4; ++mt) {
      u32x2 az2 = *(const u32x2*)(LB + (OFF_W1ZT + mt*128 + lane*2) * 4);
      u32 azv[4] = { az2.x, az2.y, 0, 0 };
      f32x16 zz = mfma32(frag4(azv), bfrag,
                         f32x16{0,0,0,0,0,0,0,0,0,0,0,0,0,0,0,0});
      #pragma unroll
      for (int q = 0; q < 4; ++q) {
        f32x4 wb = *(const f32x4*)(LB + (OFF_W2B + 32*mt + 8*q + 4*g) * 4);
        float tq[4];
        #pragma unroll
        for (int e = 0; e < 4; ++e) {
          float z  = zz[4*q + e];
          float ex = __builtin_amdgcn_exp2f(z * 2.8853900817779268f);  // e^{2z}
          float rc = __builtin_amdgcn_rcpf(ex + 1.0f);
          float tv = fmaf(-2.0f, rc, 1.0f);
          tq[e] = tv;
          w2t = fmaf(tv, wb[e], w2t);
        }
        const int kkx = 2*mt + (q >> 1), ub = 2*(q & 1);
        tf_[kkx][ub]   = pkrtz(tq[0], tq[1]);
        tf_[kkx][ub+1] = pkrtz(tq[2], tq[3]);
      }
    }

    // ---- phase 2: V = Q S^T; F2 = s . V (diag, lane-local); s = pk_fma(-t,t,1) ----
    float F2 = 0.f;
    #pragma unroll
    for (int mt = 0; mt < 4; ++mt) {
      f32x16 a = {0,0,0,0,0,0,0,0,0,0,0,0,0,0,0,0};
      #pragma unroll
      for (int kk = 0; kk < 8; ++kk) {
        u32 sfk[4];
        #pragma unroll
        for (int w = 0; w < 4; ++w) sfk[w] = s_from_t(tf_[kk][w]);
        u32x4 fr = *(const u32x4*)(LB + (OFF_QP + (mt*8 + kk)*256 + lane*4) * 4);
        a = mfma32(fragv(fr), frag4(sfk), a);
      }
      #pragma unroll
      for (int u = 0; u < 4; ++u) {
        F2 = fdot2f(s_from_t(tf_[2*mt][u]),   pkrtz(a[2*u],   a[2*u+1]), F2);
        F2 = fdot2f(s_from_t(tf_[2*mt+1][u]), pkrtz(a[8+2*u], a[9+2*u]), F2);
      }
    }

    // ---- phase 3: V2 = M2 T^T; n2 diag; u = s o (V2+w2b); G += W1 U^T ----
    float n2d = 0.f;
    f32x16 ga = {0,0,0,0,0,0,0,0,0,0,0,0,0,0,0,0};
    #pragma unroll
    for (int mt = 0; mt < 4; ++mt) {
      f32x16 a = {0,0,0,0,0,0,0,0,0,0,0,0,0,0,0,0};
      #pragma unroll
      for (int kk = 0; kk < 8; ++kk) {
        u32x4 fr = *(const u32x4*)(LB + (OFF_M2P + (mt*8 + kk)*256 + lane*4) * 4);
        a = mfma32(fragv(fr), frag4(tf_[kk]), a);
      }
      f32x4 wbq0 = *(const f32x4*)(LB + (OFF_W2B + 32*mt +      4*g) * 4);
      f32x4 wbq1 = *(const f32x4*)(LB + (OFF_W2B + 32*mt +  8 + 4*g) * 4);
      f32x4 wbq2 = *(const f32x4*)(LB + (OFF_W2B + 32*mt + 16 + 4*g) * 4);
      f32x4 wbq3 = *(const f32x4*)(LB + (OFF_W2B + 32*mt + 24 + 4*g) * 4);
      u32 ub0[4], ub1[4];
      #pragma unroll
      for (int u = 0; u < 4; ++u) {
        n2d = fdot2f(tf_[2*mt][u],   pkrtz(a[2*u],   a[2*u+1]), n2d);
        n2d = fdot2f(tf_[2*mt+1][u], pkrtz(a[8+2*u], a[9+2*u]), n2d);
        const int e = (2*u) & 3;
        f32x4 wlo = (u < 2) ? wbq0 : wbq1;
        f32x4 whi = (u < 2) ? wbq2 : wbq3;
        ub0[u] = pkmul(s_from_t(tf_[2*mt][u]),
                       pkrtz(a[2*u]   + wlo[e], a[2*u+1] + wlo[e+1]));
        ub1[u] = pkmul(s_from_t(tf_[2*mt+1][u]),
                       pkrtz(a[8+2*u] + whi[e], a[9+2*u] + whi[e+1]));
      }
      u32x4 f0 = *(const u32x4*)(LB + (OFF_W1H + (2*mt)*256   + lane*4) * 4);
      ga = mfma32(fragv(f0), frag4(ub0), ga);
      u32x4 f1 = *(const u32x4*)(LB + (OFF_W1H + (2*mt+1)*256 + lane*4) * 4);
      ga = mfma32(fragv(f1), frag4(ub1), ga);
    }
    float p2g = ga[0]*ga[0] + ga[1]*ga[1] + ga[2]*ga[2];
    if (g == 0) p2g = fmaf(ga[3], ga[3], p2g);   // j=0..3 | j=4..6

    // ---- half-wave reductions (col = lane&31 fixed) ----
    F2  += __shfl_xor(F2, 32);
    n2d += __shfl_xor(n2d, 32);
    w2t += __shfl_xor(w2t, 32);
    p2g += __shfl_xor(p2g, 32);

    if ((lane >> 5) == t) {   // this half-wave owns tile t's samples (lane = 32t+cs)
      float n2 = n2d + 2.0f*w2t + c2v;
      float v  = sqrtf(fabsf(detv) + 1e-10f);
      float nn = sqrtf(fmaxf(n2, 0.0f));
      float rr = fmaf(v, nn, 1e-8f);
      float a2 = 7.0f * v * v / (rr * rr);
      float be = v / (rr * nn + 1e-20f);
      float fac = be * (2.0f - be * n2);
      float dual = a2 * (F2 - fac * p2g);
      float dm1 = detv - 1.0f, nm7 = n2 - 7.0f;
      acc += F2 + dual + dm1*dm1 + nm7*nm7 + lposv;
    }
  }

  // ---- block reduction (clobbers weight LDS; all waves done) ----
  __syncthreads();
  float* SFw = (float*)SMEM;
  SFw[tid] = acc;
  __syncthreads();
  #pragma unroll
  for (int s = 256; s > 0; s >>= 1) {
    if (tid < s) SFw[tid] += SFw[tid + s];
    __syncthreads();
  }
  if (tid == 0) partials[blockIdx.x] = SFw[0];
}

__global__ void g2_finish(const float* __restrict__ partials, float* __restrict__ out) {
  __shared__ float red[256];
  int t = threadIdx.x;
  red[t] = partials[t] + partials[t + 256];
  __syncthreads();
  #pragma unroll
  for (int s = 128; s > 0; s >>= 1) {
    if (t < s) red[t] += red[t + s];
    __syncthreads();
  }
  if (t == 0) out[0] = red[0] * (1.0f / (float)B_TOTAL);
}

extern "C" void kernel_launch(void* const* d_in, const int* in_sizes, int n_in,
                              void* d_out, int out_size, void* d_ws, size_t ws_size,
                              hipStream_t stream) {
  (void)in_sizes; (void)n_in; (void)out_size; (void)ws_size;
  const float* coords = (const float*)d_in[0];
  const float* metric = (const float*)d_in[1];
  const float* W1     = (const float*)d_in[2];
  const float* b1     = (const float*)d_in[3];
  const float* W2     = (const float*)d_in[4];
  const float* b2     = (const float*)d_in[5];
  float* out = (float*)d_out;

  u32* ws = (u32*)d_ws;
  float* partials = (float*)(ws + NW_U32);

  g2_prep<<<43, 256, 0, stream>>>(W1, b1, W2, b2, ws);
  g2_main<<<NBLK, 512, 0, stream>>>(coords, metric, ws, partials);
  g2_finish<<<1, 256, 0, stream>>>(partials, out);
}

// Round 12
// 51.678 us; speedup vs baseline: 2.8389x; 2.8389x over previous
//
#include <hip/hip_runtime.h>

typedef _Float16 f16;
typedef f16 f16x2 __attribute__((ext_vector_type(2)));
typedef f16 f16x8 __attribute__((ext_vector_type(8)));
typedef float f32x4 __attribute__((ext_vector_type(4)));
typedef unsigned int u32;
typedef u32 u32x2 __attribute__((ext_vector_type(2)));
typedef u32 u32x4 __attribute__((ext_vector_type(4)));

#define B_TOTAL 262144
#define NBLK    512
#define SWEEPS  2      // 32 samples per sweep; 512 blk * 8 waves * 2 * 32 = 262144

// ---- ws / LDS layout (u32 indices), all frags lane-contiguous (conflict-free) ----
#define OFF_QP   0       // Q frags:  [8 mt][4 kk][64 lane][4 u32] = 8192
#define OFF_M2P  8192    // M2 frags: same = 8192
#define OFF_W1H  16384   // W1 A-frags (rows j=lane&15, zero j>=7): [4 kk][64 lane][4 u32] = 1024
#define OFF_W1Z  17408   // W1z A-frags: [8 mt][64 lane][2 u32] = 1024 (k-slots j; j==7 -> b1)
#define OFF_W2B  18432   // w2b = W2*b2: f32[128]
#define IDX_C2   18560   // ||b2||^2
#define NW_U32   18564   // = 4641 u32x4

static __device__ inline u32 pkrtz(float a, float b) {
  auto r = __builtin_amdgcn_cvt_pkrtz(a, b);
  return __builtin_bit_cast(u32, r);
}
static __device__ inline f16x8 frag4(const u32 v[4]) {
  u32x4 t = { v[0], v[1], v[2], v[3] };
  return __builtin_bit_cast(f16x8, t);
}
static __device__ inline f16x8 fragv(u32x4 v) { return __builtin_bit_cast(f16x8, v); }
static __device__ inline f32x4 mfma16(f16x8 a, f16x8 b, f32x4 c) {
  return __builtin_amdgcn_mfma_f32_16x16x32_f16(a, b, c, 0, 0, 0);
}
static __device__ inline float fdot2f(u32 a, u32 b, float c) {
  return __builtin_amdgcn_fdot2(__builtin_bit_cast(f16x2, a),
                                __builtin_bit_cast(f16x2, b), c, false);
}
// s = 1 - t^2 as one packed v_pk_fma_f16 (rematerialized at each use; no persistent sf_)
static __device__ inline u32 s_from_t(u32 t) {
  f16x2 tv = __builtin_bit_cast(f16x2, t);
  f16x2 one = { (f16)1.0f, (f16)1.0f };
  f16x2 sv = __builtin_elementwise_fma(-tv, tv, one);
  return __builtin_bit_cast(u32, sv);
}
static __device__ inline u32 pkmul(u32 a, u32 b) {
  f16x2 r = __builtin_bit_cast(f16x2, a) * __builtin_bit_cast(f16x2, b);
  return __builtin_bit_cast(u32, r);
}
// inverse of round-4's frag_remap: stored word p = 4g + w  ->  logical pair offset o
static __device__ inline int inv_remap(int g, int w) {
  return ((w & 2) == 0) ? (2*g + (w & 1)) : (8 + 2*g + (w & 1));
}

// Jacobi fallback (only if a GE pivot is tiny -- never for this data distribution)
__device__ __noinline__ void eig7_fallback(const float* Mg, float* det_o, float* lpos_o) {
  float a[49];
  for (int i = 0; i < 49; ++i) a[i] = Mg[i];
  for (int sw = 0; sw < 10; ++sw)
    for (int p = 0; p < 6; ++p)
      for (int q = p + 1; q < 7; ++q) {
        float apq = a[p*7+q];
        if (fabsf(apq) < 1e-12f) continue;
        float th = 0.5f*(a[q*7+q] - a[p*7+p]) / apq;
        float tt = 1.0f/(fabsf(th) + sqrtf(th*th + 1.0f));
        if (th < 0.0f) tt = -tt;
        float cc = 1.0f/sqrtf(tt*tt + 1.0f), ss = tt*cc;
        for (int i = 0; i < 7; ++i) {
          float aip = a[i*7+p], aiq = a[i*7+q];
          a[i*7+p] = cc*aip - ss*aiq; a[i*7+q] = ss*aip + cc*aiq;
        }
        for (int i = 0; i < 7; ++i) {
          float api = a[p*7+i], aqi = a[q*7+i];
          a[p*7+i] = cc*api - ss*aqi; a[q*7+i] = ss*api + cc*aqi;
        }
      }
  float det = 1.0f, lp = 0.0f;
  for (int i = 0; i < 7; ++i) {
    float e = a[i*7+i];
    det *= e;
    float rl = fmaxf(1e-6f - e, 0.0f);
    lp += rl*rl;
  }
  *det_o = det; *lpos_o = lp * (1.0f/7.0f);
}

__global__ void g2_prep(const float* __restrict__ W1, const float* __restrict__ b1,
                        const float* __restrict__ W2, const float* __restrict__ b2,
                        u32* __restrict__ ws) {
  int gid = blockIdx.x * 256 + threadIdx.x;
  if (gid < 8192) {                         // QP + M2P frags
    int f = gid >> 8;                       // mt*4 + kk
    int lane = (gid >> 2) & 63, w = gid & 3;
    int mt = f >> 2, kk = f & 3;
    int c = lane & 15, g = lane >> 4;
    int h = 16*mt + c;
    int o = inv_remap(g, w);
    int kp = kk*16 + o, k0 = 2*kp, k1 = k0 + 1;
    float m2a = 0.f, m2b = 0.f;
    for (int x = 0; x < 35; ++x) {
      float wh = W2[h*35 + x];
      m2a = fmaf(wh, W2[k0*35 + x], m2a);
      m2b = fmaf(wh, W2[k1*35 + x], m2b);
    }
    float n1a = 0.f, n1b = 0.f;
    for (int j = 0; j < 7; ++j) {
      float wj = W1[j*128 + h];
      n1a = fmaf(wj, W1[j*128 + k0], n1a);
      n1b = fmaf(wj, W1[j*128 + k1], n1b);
    }
    ws[OFF_QP  + gid] = pkrtz(m2a*n1a, m2b*n1b);
    ws[OFF_M2P + gid] = pkrtz(m2a, m2b);
  } else if (gid < 9216) {                  // W1H A-frags: rows j = lane&15 (>=7 zero)
    int idx = gid - 8192;
    int kk = idx >> 8, lane = (idx >> 2) & 63, w = idx & 3;
    int j = lane & 15, g = lane >> 4;
    int o = inv_remap(g, w);
    int kp = kk*16 + o, k0 = 2*kp, k1 = k0 + 1;
    float a = 0.f, b = 0.f;
    if (j < 7) { a = W1[j*128 + k0]; b = W1[j*128 + k1]; }
    ws[OFF_W1H + idx] = pkrtz(a, b);
  } else if (gid < 10240) {                 // W1Z A-frags: row h, k-slots j (j==7 -> b1)
    int idx = gid - 9216;
    int mt = idx >> 7, r = idx & 127, lane = r >> 1, half = r & 1;
    int c = lane & 15, g = lane >> 4;
    int h = 16*mt + c;
    float a = 0.f, b = 0.f;
    if (g < 2) {
      int jp = 2*g + half, j0 = 2*jp, j1 = j0 + 1;
      a = W1[j0*128 + h];
      b = (j1 < 7) ? W1[j1*128 + h] : b1[h];
    }
    ws[OFF_W1Z + (mt*64 + lane)*2 + half] = pkrtz(a, b);
  } else if (gid < 10368) {                 // w2b = W2 b2
    int h = gid - 10240;
    float s = 0.f;
    for (int x = 0; x < 35; ++x) s = fmaf(W2[h*35 + x], b2[x], s);
    ws[OFF_W2B + h] = __builtin_bit_cast(u32, s);
  } else if (gid == 10368) {                // c2 = ||b2||^2
    float s = 0.f;
    for (int x = 0; x < 35; ++x) s = fmaf(b2[x], b2[x], s);
    ws[IDX_C2] = __builtin_bit_cast(u32, s);
  }
}

__global__ __launch_bounds__(512, 2) void g2_main(
    const float* __restrict__ coords, const float* __restrict__ metric,
    const u32* __restrict__ wsW, float* __restrict__ partials) {
  __shared__ __align__(16) u32 SMEM[NW_U32];
  const int tid = threadIdx.x;

  { // stage weights: 4641 uint4
    const u32x4* src = (const u32x4*)wsW;
    u32x4* dst = (u32x4*)SMEM;
    #pragma unroll
    for (int i = 0; i < 10; ++i) {
      int idx = tid + 512 * i;
      if (idx < 4641) dst[idx] = src[idx];
    }
  }
  __syncthreads();

  const int lane = tid & 63, wv = tid >> 6;
  const int g = lane >> 4, c = lane & 15;
  const int wave_gid = blockIdx.x * 8 + wv;
  const int sbase = wave_gid * 64;
  const char* LB = (const char*)SMEM;
  const float c2v = ((const float*)SMEM)[IDX_C2];

  // ---- dets for all 64 samples up-front (symmetric GE on lower triangle) ----
  float detv = 1.f, lposv = 0.f;
  {
    const float* Mg = metric + (size_t)(sbase + lane) * 49;
    float m[28];
    #pragma unroll
    for (int i = 0; i < 7; ++i)
      #pragma unroll
      for (int j = 0; j <= i; ++j)
        m[i*(i+1)/2 + j] = Mg[i*7 + j];
    float minpiv = 3.4e38f;
    #pragma unroll
    for (int k = 0; k < 7; ++k) {
      float piv = m[k*(k+1)/2 + k];
      minpiv = fminf(minpiv, piv);
      detv *= piv;
      float inv = 1.0f / piv;
      #pragma unroll
      for (int i = k + 1; i < 7; ++i) {
        float f = m[i*(i+1)/2 + k] * inv;
        #pragma unroll
        for (int j = k + 1; j <= i; ++j)
          m[i*(i+1)/2 + j] = fmaf(-f, m[j*(j+1)/2 + k], m[i*(i+1)/2 + j]);
      }
    }
    if (!(minpiv > 1e-4f)) eig7_fallback(Mg, &detv, &lposv);
  }

  float acc = 0.f;

  #pragma unroll 1
  for (int t = 0; t < SWEEPS; ++t) {
    const int sb = sbase + 32*t;

    // ---- phase 1: Z = W1z^T C via MFMA for BOTH 16-col tiles; tanh -> tfa/tfb ----
    const float* cgA = coords + (size_t)(sb + c) * 7;
    const float* cgB = cgA + 16*7;
    u32 bA[4] = {0,0,0,0}, bB[4] = {0,0,0,0};
    if (g == 0) {
      bA[0] = pkrtz(cgA[0], cgA[1]); bA[1] = pkrtz(cgA[2], cgA[3]);
      bB[0] = pkrtz(cgB[0], cgB[1]); bB[1] = pkrtz(cgB[2], cgB[3]);
    } else if (g == 1) {
      bA[0] = pkrtz(cgA[4], cgA[5]); bA[1] = pkrtz(cgA[6], 1.0f);
      bB[0] = pkrtz(cgB[4], cgB[5]); bB[1] = pkrtz(cgB[6], 1.0f);
    }
    const f16x8 bfA = frag4(bA), bfB = frag4(bB);

    u32 tfa[4][4], tfb[4][4];
    float w2ta = 0.f, w2tb = 0.f;
    #pragma unroll 2
    for (int mt = 0; mt < 8; ++mt) {
      u32x2 az2 = *(const u32x2*)(LB + (OFF_W1Z + (mt*64 + lane)*2) * 4);
      u32 azv[4] = { az2.x, az2.y, 0, 0 };
      const f16x8 afr = frag4(azv);
      f32x4 zzA = mfma16(afr, bfA, f32x4{0.f,0.f,0.f,0.f});
      f32x4 zzB = mfma16(afr, bfB, f32x4{0.f,0.f,0.f,0.f});
      f32x4 wb = *(const f32x4*)(LB + (OFF_W2B + 16*mt + 4*g) * 4);
      float tA[4], tB[4];
      #pragma unroll
      for (int e = 0; e < 4; ++e) {
        float exA = __builtin_amdgcn_exp2f(zzA[e] * 2.8853900817779268f);  // e^{2z}
        float tvA = fmaf(-2.0f, __builtin_amdgcn_rcpf(exA + 1.0f), 1.0f);
        tA[e] = tvA; w2ta = fmaf(tvA, wb[e], w2ta);
        float exB = __builtin_amdgcn_exp2f(zzB[e] * 2.8853900817779268f);
        float tvB = fmaf(-2.0f, __builtin_amdgcn_rcpf(exB + 1.0f), 1.0f);
        tB[e] = tvB; w2tb = fmaf(tvB, wb[e], w2tb);
      }
      const int kk = mt >> 1, u0 = 2*(mt & 1);
      tfa[kk][u0]   = pkrtz(tA[0], tA[1]);
      tfa[kk][u0+1] = pkrtz(tA[2], tA[3]);
      tfb[kk][u0]   = pkrtz(tB[0], tB[1]);
      tfb[kk][u0+1] = pkrtz(tB[2], tB[3]);
    }

    // ---- phase 2: V = Q S^T (frag loaded once, 2 MFMAs); F2 diag lane-local ----
    float F2a = 0.f, F2b = 0.f;
    #pragma unroll 2
    for (int mt = 0; mt < 8; ++mt) {
      f32x4 va = {0.f,0.f,0.f,0.f}, vb = {0.f,0.f,0.f,0.f};
      #pragma unroll
      for (int kk = 0; kk < 4; ++kk) {
        u32x4 fr = *(const u32x4*)(LB + (OFF_QP + ((mt*4 + kk)*64 + lane)*4) * 4);
        const f16x8 qa = fragv(fr);
        u32 sA[4], sB[4];
        #pragma unroll
        for (int w = 0; w < 4; ++w) { sA[w] = s_from_t(tfa[kk][w]); sB[w] = s_from_t(tfb[kk][w]); }
        va = mfma16(qa, frag4(sA), va);
        vb = mfma16(qa, frag4(sB), vb);
      }
      const int kk2 = mt >> 1, u0 = 2*(mt & 1);
      F2a = fdot2f(s_from_t(tfa[kk2][u0]),   pkrtz(va[0], va[1]), F2a);
      F2a = fdot2f(s_from_t(tfa[kk2][u0+1]), pkrtz(va[2], va[3]), F2a);
      F2b = fdot2f(s_from_t(tfb[kk2][u0]),   pkrtz(vb[0], vb[1]), F2b);
      F2b = fdot2f(s_from_t(tfb[kk2][u0+1]), pkrtz(vb[2], vb[3]), F2b);
    }

    // ---- phase 3 fused: V2 = M2 T^T; n2 diag; u = s o (V2+w2b); G += W1 U^T ----
    float n2a = 0.f, n2b = 0.f;
    f32x4 gaa = {0.f,0.f,0.f,0.f}, gab = {0.f,0.f,0.f,0.f};
    u32 upA0 = 0, upA1 = 0, upB0 = 0, upB1 = 0;
    #pragma unroll 2
    for (int mt = 0; mt < 8; ++mt) {
      f32x4 va = {0.f,0.f,0.f,0.f}, vb = {0.f,0.f,0.f,0.f};
      #pragma unroll
      for (int kk = 0; kk < 4; ++kk) {
        u32x4 fr = *(const u32x4*)(LB + (OFF_M2P + ((mt*4 + kk)*64 + lane)*4) * 4);
        const f16x8 qa = fragv(fr);
        va = mfma16(qa, frag4(tfa[kk]), va);
        vb = mfma16(qa, frag4(tfb[kk]), vb);
      }
      const int kk2 = mt >> 1, u0 = 2*(mt & 1);
      n2a = fdot2f(tfa[kk2][u0],   pkrtz(va[0], va[1]), n2a);
      n2a = fdot2f(tfa[kk2][u0+1], pkrtz(va[2], va[3]), n2a);
      n2b = fdot2f(tfb[kk2][u0],   pkrtz(vb[0], vb[1]), n2b);
      n2b = fdot2f(tfb[kk2][u0+1], pkrtz(vb[2], vb[3]), n2b);
      f32x4 wb = *(const f32x4*)(LB + (OFF_W2B + 16*mt + 4*g) * 4);
      u32 paA = pkmul(s_from_t(tfa[kk2][u0]),   pkrtz(va[0] + wb[0], va[1] + wb[1]));
      u32 pbA = pkmul(s_from_t(tfa[kk2][u0+1]), pkrtz(va[2] + wb[2], va[3] + wb[3]));
      u32 paB = pkmul(s_from_t(tfb[kk2][u0]),   pkrtz(vb[0] + wb[0], vb[1] + wb[1]));
      u32 pbB = pkmul(s_from_t(tfb[kk2][u0+1]), pkrtz(vb[2] + wb[2], vb[3] + wb[3]));
      if ((mt & 1) == 0) {
        upA0 = paA; upA1 = pbA; upB0 = paB; upB1 = pbB;
      } else {
        const int kk = mt >> 1;
        u32x4 frw = *(const u32x4*)(LB + (OFF_W1H + (kk*64 + lane)*4) * 4);
        const f16x8 wfr = fragv(frw);
        u32 uA[4] = { upA0, upA1, paA, pbA };
        u32 uB[4] = { upB0, upB1, paB, pbB };
        gaa = mfma16(wfr, frag4(uA), gaa);
        gab = mfma16(wfr, frag4(uB), gab);
      }
    }
    float p2ga = gaa[0]*gaa[0] + gaa[1]*gaa[1] + gaa[2]*gaa[2];
    float p2gb = gab[0]*gab[0] + gab[1]*gab[1] + gab[2]*gab[2];
    if (g == 0) { p2ga = fmaf(gaa[3], gaa[3], p2ga); p2gb = fmaf(gab[3], gab[3], p2gb); }

    // ---- reductions over the 4 g-groups (column c fixed) ----
    F2a += __shfl_xor(F2a, 16); F2a += __shfl_xor(F2a, 32);
    F2b += __shfl_xor(F2b, 16); F2b += __shfl_xor(F2b, 32);
    n2a += __shfl_xor(n2a, 16); n2a += __shfl_xor(n2a, 32);
    n2b += __shfl_xor(n2b, 16); n2b += __shfl_xor(n2b, 32);
    w2ta += __shfl_xor(w2ta, 16); w2ta += __shfl_xor(w2ta, 32);
    w2tb += __shfl_xor(w2tb, 16); w2tb += __shfl_xor(w2tb, 32);
    p2ga += __shfl_xor(p2ga, 16); p2ga += __shfl_xor(p2ga, 32);
    p2gb += __shfl_xor(p2gb, 16); p2gb += __shfl_xor(p2gb, 32);

    const float det0 = __shfl(detv,  32*t + c);
    const float lp0  = __shfl(lposv, 32*t + c);
    const float det1 = __shfl(detv,  32*t + 16 + c);
    const float lp1  = __shfl(lposv, 32*t + 16 + c);

    // tile 0 finalized on g==0 lanes, tile 1 on g==1 lanes (block-sum adds all lanes)
    {
      float F2 = (g == 0) ? F2a : F2b;
      float n2d = (g == 0) ? n2a : n2b;
      float w2t = (g == 0) ? w2ta : w2tb;
      float p2g = (g == 0) ? p2ga : p2gb;
      float det = (g == 0) ? det0 : det1;
      float lpo = (g == 0) ? lp0 : lp1;
      if (g < 2) {
        float n2 = n2d + 2.0f*w2t + c2v;
        float v  = sqrtf(fabsf(det) + 1e-10f);
        float nn = sqrtf(fmaxf(n2, 0.0f));
        float rr = fmaf(v, nn, 1e-8f);
        float a2 = 7.0f * v * v / (rr * rr);
        float be = v / (rr * nn + 1e-20f);
        float fac = be * (2.0f - be * n2);
        float dual = a2 * (F2 - fac * p2g);
        float dm1 = det - 1.0f, nm7 = n2 - 7.0f;
        acc += F2 + dual + dm1*dm1 + nm7*nm7 + lpo;
      }
    }
  }

  // ---- block reduction (clobbers weight LDS; all waves done) ----
  __syncthreads();
  float* SFw = (float*)SMEM;
  SFw[tid] = acc;
  __syncthreads();
  #pragma unroll
  for (int s = 256; s > 0; s >>= 1) {
    if (tid < s) SFw[tid] += SFw[tid + s];
    __syncthreads();
  }
  if (tid == 0) partials[blockIdx.x] = SFw[0];
}

__global__ void g2_finish(const float* __restrict__ partials, float* __restrict__ out) {
  __shared__ float red[256];
  int t = threadIdx.x;
  red[t] = partials[t] + partials[t + 256];
  __syncthreads();
  #pragma unroll
  for (int s = 128; s > 0; s >>= 1) {
    if (t < s) red[t] += red[t + s];
    __syncthreads();
  }
  if (t == 0) out[0] = red[0] * (1.0f / (float)B_TOTAL);
}

extern "C" void kernel_launch(void* const* d_in, const int* in_sizes, int n_in,
                              void* d_out, int out_size, void* d_ws, size_t ws_size,
                              hipStream_t stream) {
  (void)in_sizes; (void)n_in; (void)out_size; (void)ws_size;
  const float* coords = (const float*)d_in[0];
  const float* metric = (const float*)d_in[1];
  const float* W1     = (const float*)d_in[2];
  const float* b1     = (const float*)d_in[3];
  const float* W2     = (const float*)d_in[4];
  const float* b2     = (const float*)d_in[5];
  float* out = (float*)d_out;

  u32* ws = (u32*)d_ws;
  float* partials = (float*)(ws + NW_U32);

  g2_prep<<<41, 256, 0, stream>>>(W1, b1, W2, b2, ws);
  g2_main<<<NBLK, 512, 0, stream>>>(coords, metric, ws, partials);
  g2_finish<<<1, 256, 0, stream>>>(partials, out);
}

// Round 13
// 51.212 us; speedup vs baseline: 2.8647x; 1.0091x over previous
//
#include <hip/hip_runtime.h>

typedef _Float16 f16;
typedef f16 f16x2 __attribute__((ext_vector_type(2)));
typedef f16 f16x8 __attribute__((ext_vector_type(8)));
typedef float f32x4 __attribute__((ext_vector_type(4)));
typedef unsigned int u32;
typedef u32 u32x2 __attribute__((ext_vector_type(2)));
typedef u32 u32x4 __attribute__((ext_vector_type(4)));

#define B_TOTAL 262144
#define NBLK    512
#define SWEEPS  2      // 32 samples per sweep; 512 blk * 8 waves * 2 * 32 = 262144

// ---- ws / LDS layout (u32 indices), all frags lane-contiguous (conflict-free) ----
#define OFF_QP   0       // Q frags:  [8 mt][4 kk][64 lane][4 u32] = 8192
#define OFF_M2P  8192    // M2 frags: same = 8192
#define OFF_W1H  16384   // W1 A-frags (rows j=lane&15, zero j>=7): [4 kk][64 lane][4 u32] = 1024
#define OFF_W1Z  17408   // W1z A-frags: [8 mt][64 lane][2 u32] = 1024 (k-slots j; j==7 -> b1)
#define OFF_W2B  18432   // w2b = W2*b2: f32[128]
#define IDX_C2   18560   // ||b2||^2
#define NW_U32   18564   // = 4641 u32x4

static __device__ inline u32 pkrtz(float a, float b) {
  auto r = __builtin_amdgcn_cvt_pkrtz(a, b);
  return __builtin_bit_cast(u32, r);
}
static __device__ inline f16x8 frag4(const u32 v[4]) {
  u32x4 t = { v[0], v[1], v[2], v[3] };
  return __builtin_bit_cast(f16x8, t);
}
static __device__ inline f16x8 fragv(u32x4 v) { return __builtin_bit_cast(f16x8, v); }
static __device__ inline f32x4 mfma16(f16x8 a, f16x8 b, f32x4 c) {
  return __builtin_amdgcn_mfma_f32_16x16x32_f16(a, b, c, 0, 0, 0);
}
static __device__ inline float fdot2f(u32 a, u32 b, float c) {
  return __builtin_amdgcn_fdot2(__builtin_bit_cast(f16x2, a),
                                __builtin_bit_cast(f16x2, b), c, false);
}
// s = 1 - t^2 as one packed v_pk_fma_f16
static __device__ inline u32 s_from_t(u32 t) {
  f16x2 tv = __builtin_bit_cast(f16x2, t);
  f16x2 one = { (f16)1.0f, (f16)1.0f };
  f16x2 sv = __builtin_elementwise_fma(-tv, tv, one);
  return __builtin_bit_cast(u32, sv);
}
static __device__ inline u32 pkmul(u32 a, u32 b) {
  f16x2 r = __builtin_bit_cast(f16x2, a) * __builtin_bit_cast(f16x2, b);
  return __builtin_bit_cast(u32, r);
}
// inverse of the frag remap: stored word p = 4g + w  ->  logical pair offset o
static __device__ inline int inv_remap(int g, int w) {
  return ((w & 2) == 0) ? (2*g + (w & 1)) : (8 + 2*g + (w & 1));
}

// Jacobi fallback (only if a GE pivot is tiny -- never for this data distribution)
__device__ __noinline__ void eig7_fallback(const float* Mg, float* det_o, float* lpos_o) {
  float a[49];
  for (int i = 0; i < 49; ++i) a[i] = Mg[i];
  for (int sw = 0; sw < 10; ++sw)
    for (int p = 0; p < 6; ++p)
      for (int q = p + 1; q < 7; ++q) {
        float apq = a[p*7+q];
        if (fabsf(apq) < 1e-12f) continue;
        float th = 0.5f*(a[q*7+q] - a[p*7+p]) / apq;
        float tt = 1.0f/(fabsf(th) + sqrtf(th*th + 1.0f));
        if (th < 0.0f) tt = -tt;
        float cc = 1.0f/sqrtf(tt*tt + 1.0f), ss = tt*cc;
        for (int i = 0; i < 7; ++i) {
          float aip = a[i*7+p], aiq = a[i*7+q];
          a[i*7+p] = cc*aip - ss*aiq; a[i*7+q] = ss*aip + cc*aiq;
        }
        for (int i = 0; i < 7; ++i) {
          float api = a[p*7+i], aqi = a[q*7+i];
          a[p*7+i] = cc*api - ss*aqi; a[q*7+i] = ss*api + cc*aqi;
        }
      }
  float det = 1.0f, lp = 0.0f;
  for (int i = 0; i < 7; ++i) {
    float e = a[i*7+i];
    det *= e;
    float rl = fmaxf(1e-6f - e, 0.0f);
    lp += rl*rl;
  }
  *det_o = det; *lpos_o = lp * (1.0f/7.0f);
}

__global__ void g2_prep(const float* __restrict__ W1, const float* __restrict__ b1,
                        const float* __restrict__ W2, const float* __restrict__ b2,
                        u32* __restrict__ ws) {
  int gid = blockIdx.x * 256 + threadIdx.x;
  if (gid < 8192) {                         // QP + M2P frags
    int f = gid >> 8;                       // mt*4 + kk
    int lane = (gid >> 2) & 63, w = gid & 3;
    int mt = f >> 2, kk = f & 3;
    int c = lane & 15, g = lane >> 4;
    int h = 16*mt + c;
    int o = inv_remap(g, w);
    int kp = kk*16 + o, k0 = 2*kp, k1 = k0 + 1;
    float m2a = 0.f, m2b = 0.f;
    for (int x = 0; x < 35; ++x) {
      float wh = W2[h*35 + x];
      m2a = fmaf(wh, W2[k0*35 + x], m2a);
      m2b = fmaf(wh, W2[k1*35 + x], m2b);
    }
    float n1a = 0.f, n1b = 0.f;
    for (int j = 0; j < 7; ++j) {
      float wj = W1[j*128 + h];
      n1a = fmaf(wj, W1[j*128 + k0], n1a);
      n1b = fmaf(wj, W1[j*128 + k1], n1b);
    }
    ws[OFF_QP  + gid] = pkrtz(m2a*n1a, m2b*n1b);
    ws[OFF_M2P + gid] = pkrtz(m2a, m2b);
  } else if (gid < 9216) {                  // W1H A-frags: rows j = lane&15 (>=7 zero)
    int idx = gid - 8192;
    int kk = idx >> 8, lane = (idx >> 2) & 63, w = idx & 3;
    int j = lane & 15, g = lane >> 4;
    int o = inv_remap(g, w);
    int kp = kk*16 + o, k0 = 2*kp, k1 = k0 + 1;
    float a = 0.f, b = 0.f;
    if (j < 7) { a = W1[j*128 + k0]; b = W1[j*128 + k1]; }
    ws[OFF_W1H + idx] = pkrtz(a, b);
  } else if (gid < 10240) {                 // W1Z A-frags: row h, k-slots j (j==7 -> b1)
    int idx = gid - 9216;
    int mt = idx >> 7, r = idx & 127, lane = r >> 1, half = r & 1;
    int c = lane & 15, g = lane >> 4;
    int h = 16*mt + c;
    float a = 0.f, b = 0.f;
    if (g < 2) {
      int jp = 2*g + half, j0 = 2*jp, j1 = j0 + 1;
      a = W1[j0*128 + h];
      b = (j1 < 7) ? W1[j1*128 + h] : b1[h];
    }
    ws[OFF_W1Z + (mt*64 + lane)*2 + half] = pkrtz(a, b);
  } else if (gid < 10368) {                 // w2b = W2 b2
    int h = gid - 10240;
    float s = 0.f;
    for (int x = 0; x < 35; ++x) s = fmaf(W2[h*35 + x], b2[x], s);
    ws[OFF_W2B + h] = __builtin_bit_cast(u32, s);
  } else if (gid == 10368) {                // c2 = ||b2||^2
    float s = 0.f;
    for (int x = 0; x < 35; ++x) s = fmaf(b2[x], b2[x], s);
    ws[IDX_C2] = __builtin_bit_cast(u32, s);
  }
}

__global__ __launch_bounds__(512, 2) void g2_main(
    const float* __restrict__ coords, const float* __restrict__ metric,
    const u32* __restrict__ wsW, float* __restrict__ partials) {
  __shared__ __align__(16) u32 SMEM[NW_U32];
  const int tid = threadIdx.x;

  { // stage weights: 4641 uint4
    const u32x4* src = (const u32x4*)wsW;
    u32x4* dst = (u32x4*)SMEM;
    #pragma unroll
    for (int i = 0; i < 10; ++i) {
      int idx = tid + 512 * i;
      if (idx < 4641) dst[idx] = src[idx];
    }
  }
  __syncthreads();

  const int lane = tid & 63, wv = tid >> 6;
  const int g = lane >> 4, c = lane & 15;
  const int wave_gid = blockIdx.x * 8 + wv;
  const int sbase = wave_gid * 64;
  const char* LB = (const char*)SMEM;
  const float c2v = ((const float*)SMEM)[IDX_C2];

  // ---- dets for all 64 samples up-front (symmetric GE on lower triangle) ----
  float detv = 1.f, lposv = 0.f;
  {
    const float* Mg = metric + (size_t)(sbase + lane) * 49;
    float m[28];
    #pragma unroll
    for (int i = 0; i < 7; ++i)
      #pragma unroll
      for (int j = 0; j <= i; ++j)
        m[i*(i+1)/2 + j] = Mg[i*7 + j];
    float minpiv = 3.4e38f;
    #pragma unroll
    for (int k = 0; k < 7; ++k) {
      float piv = m[k*(k+1)/2 + k];
      minpiv = fminf(minpiv, piv);
      detv *= piv;
      float inv = 1.0f / piv;
      #pragma unroll
      for (int i = k + 1; i < 7; ++i) {
        float f = m[i*(i+1)/2 + k] * inv;
        #pragma unroll
        for (int j = k + 1; j <= i; ++j)
          m[i*(i+1)/2 + j] = fmaf(-f, m[j*(j+1)/2 + k], m[i*(i+1)/2 + j]);
      }
    }
    if (!(minpiv > 1e-4f)) eig7_fallback(Mg, &detv, &lposv);
  }

  float acc = 0.f;

  #pragma unroll 1
  for (int t = 0; t < SWEEPS; ++t) {
    const int sb = sbase + 32*t;

    // ---- phase 1: Z = W1z^T C via MFMA for BOTH 16-col tiles; tanh -> tfa/tfb ----
    const float* cgA = coords + (size_t)(sb + c) * 7;
    const float* cgB = cgA + 16*7;
    u32 bA[4] = {0,0,0,0}, bB[4] = {0,0,0,0};
    if (g == 0) {
      bA[0] = pkrtz(cgA[0], cgA[1]); bA[1] = pkrtz(cgA[2], cgA[3]);
      bB[0] = pkrtz(cgB[0], cgB[1]); bB[1] = pkrtz(cgB[2], cgB[3]);
    } else if (g == 1) {
      bA[0] = pkrtz(cgA[4], cgA[5]); bA[1] = pkrtz(cgA[6], 1.0f);
      bB[0] = pkrtz(cgB[4], cgB[5]); bB[1] = pkrtz(cgB[6], 1.0f);
    }
    const f16x8 bfA = frag4(bA), bfB = frag4(bB);

    u32 tfa[4][4], tfb[4][4];
    float w2ta = 0.f, w2tb = 0.f;
    #pragma unroll 2
    for (int mt = 0; mt < 8; ++mt) {
      u32x2 az2 = *(const u32x2*)(LB + (OFF_W1Z + (mt*64 + lane)*2) * 4);
      u32 azv[4] = { az2.x, az2.y, 0, 0 };
      const f16x8 afr = frag4(azv);
      f32x4 zzA = mfma16(afr, bfA, f32x4{0.f,0.f,0.f,0.f});
      f32x4 zzB = mfma16(afr, bfB, f32x4{0.f,0.f,0.f,0.f});
      f32x4 wb = *(const f32x4*)(LB + (OFF_W2B + 16*mt + 4*g) * 4);
      float tA[4], tB[4];
      #pragma unroll
      for (int e = 0; e < 4; ++e) {
        float exA = __builtin_amdgcn_exp2f(zzA[e] * 2.8853900817779268f);  // e^{2z}
        float tvA = fmaf(-2.0f, __builtin_amdgcn_rcpf(exA + 1.0f), 1.0f);
        tA[e] = tvA; w2ta = fmaf(tvA, wb[e], w2ta);
        float exB = __builtin_amdgcn_exp2f(zzB[e] * 2.8853900817779268f);
        float tvB = fmaf(-2.0f, __builtin_amdgcn_rcpf(exB + 1.0f), 1.0f);
        tB[e] = tvB; w2tb = fmaf(tvB, wb[e], w2tb);
      }
      const int kk = mt >> 1, u0 = 2*(mt & 1);
      tfa[kk][u0]   = pkrtz(tA[0], tA[1]);
      tfa[kk][u0+1] = pkrtz(tA[2], tA[3]);
      tfb[kk][u0]   = pkrtz(tB[0], tB[1]);
      tfb[kk][u0+1] = pkrtz(tB[2], tB[3]);
    }

    // ---- hoisted s-fragments (once per sweep, 32 packed ops) ----
    u32 sfa[4][4], sfb[4][4];
    #pragma unroll
    for (int kk = 0; kk < 4; ++kk)
      #pragma unroll
      for (int w = 0; w < 4; ++w) {
        sfa[kk][w] = s_from_t(tfa[kk][w]);
        sfb[kk][w] = s_from_t(tfb[kk][w]);
      }

    // ---- merged phase 2+3: one sweep, 4 indep MFMAs per (mt,kk) load pair ----
    float F2a = 0.f, F2b = 0.f, n2a = 0.f, n2b = 0.f;
    f32x4 gaa = {0.f,0.f,0.f,0.f}, gab = {0.f,0.f,0.f,0.f};
    u32 upA0 = 0, upA1 = 0, upB0 = 0, upB1 = 0;
    #pragma unroll 2
    for (int mt = 0; mt < 8; ++mt) {
      f32x4 qa_ = {0.f,0.f,0.f,0.f}, qb_ = {0.f,0.f,0.f,0.f};
      f32x4 ma_ = {0.f,0.f,0.f,0.f}, mb_ = {0.f,0.f,0.f,0.f};
      #pragma unroll
      for (int kk = 0; kk < 4; ++kk) {
        u32x4 frq = *(const u32x4*)(LB + (OFF_QP  + ((mt*4 + kk)*64 + lane)*4) * 4);
        u32x4 frm = *(const u32x4*)(LB + (OFF_M2P + ((mt*4 + kk)*64 + lane)*4) * 4);
        const f16x8 qf = fragv(frq), mf = fragv(frm);
        qa_ = mfma16(qf, frag4(sfa[kk]), qa_);
        qb_ = mfma16(qf, frag4(sfb[kk]), qb_);
        ma_ = mfma16(mf, frag4(tfa[kk]), ma_);
        mb_ = mfma16(mf, frag4(tfb[kk]), mb_);
      }
      const int kk2 = mt >> 1, u0 = 2*(mt & 1);
      // F2 diag (Q sweep)
      F2a = fdot2f(sfa[kk2][u0],   pkrtz(qa_[0], qa_[1]), F2a);
      F2a = fdot2f(sfa[kk2][u0+1], pkrtz(qa_[2], qa_[3]), F2a);
      F2b = fdot2f(sfb[kk2][u0],   pkrtz(qb_[0], qb_[1]), F2b);
      F2b = fdot2f(sfb[kk2][u0+1], pkrtz(qb_[2], qb_[3]), F2b);
      // n2 diag (M2 sweep)
      n2a = fdot2f(tfa[kk2][u0],   pkrtz(ma_[0], ma_[1]), n2a);
      n2a = fdot2f(tfa[kk2][u0+1], pkrtz(ma_[2], ma_[3]), n2a);
      n2b = fdot2f(tfb[kk2][u0],   pkrtz(mb_[0], mb_[1]), n2b);
      n2b = fdot2f(tfb[kk2][u0+1], pkrtz(mb_[2], mb_[3]), n2b);
      // u = s o (V2 + w2b), G-MFMA every odd mt
      f32x4 wb = *(const f32x4*)(LB + (OFF_W2B + 16*mt + 4*g) * 4);
      u32 paA = pkmul(sfa[kk2][u0],   pkrtz(ma_[0] + wb[0], ma_[1] + wb[1]));
      u32 pbA = pkmul(sfa[kk2][u0+1], pkrtz(ma_[2] + wb[2], ma_[3] + wb[3]));
      u32 paB = pkmul(sfb[kk2][u0],   pkrtz(mb_[0] + wb[0], mb_[1] + wb[1]));
      u32 pbB = pkmul(sfb[kk2][u0+1], pkrtz(mb_[2] + wb[2], mb_[3] + wb[3]));
      if ((mt & 1) == 0) {
        upA0 = paA; upA1 = pbA; upB0 = paB; upB1 = pbB;
      } else {
        const int kk = mt >> 1;
        u32x4 frw = *(const u32x4*)(LB + (OFF_W1H + (kk*64 + lane)*4) * 4);
        const f16x8 wfr = fragv(frw);
        u32 uA[4] = { upA0, upA1, paA, pbA };
        u32 uB[4] = { upB0, upB1, paB, pbB };
        gaa = mfma16(wfr, frag4(uA), gaa);
        gab = mfma16(wfr, frag4(uB), gab);
      }
    }
    float p2ga = gaa[0]*gaa[0] + gaa[1]*gaa[1] + gaa[2]*gaa[2];
    float p2gb = gab[0]*gab[0] + gab[1]*gab[1] + gab[2]*gab[2];
    if (g == 0) { p2ga = fmaf(gaa[3], gaa[3], p2ga); p2gb = fmaf(gab[3], gab[3], p2gb); }

    // ---- reductions over the 4 g-groups (column c fixed) ----
    F2a += __shfl_xor(F2a, 16); F2a += __shfl_xor(F2a, 32);
    F2b += __shfl_xor(F2b, 16); F2b += __shfl_xor(F2b, 32);
    n2a += __shfl_xor(n2a, 16); n2a += __shfl_xor(n2a, 32);
    n2b += __shfl_xor(n2b, 16); n2b += __shfl_xor(n2b, 32);
    w2ta += __shfl_xor(w2ta, 16); w2ta += __shfl_xor(w2ta, 32);
    w2tb += __shfl_xor(w2tb, 16); w2tb += __shfl_xor(w2tb, 32);
    p2ga += __shfl_xor(p2ga, 16); p2ga += __shfl_xor(p2ga, 32);
    p2gb += __shfl_xor(p2gb, 16); p2gb += __shfl_xor(p2gb, 32);

    const float det0 = __shfl(detv,  32*t + c);
    const float lp0  = __shfl(lposv, 32*t + c);
    const float det1 = __shfl(detv,  32*t + 16 + c);
    const float lp1  = __shfl(lposv, 32*t + 16 + c);

    // tile 0 finalized on g==0 lanes, tile 1 on g==1 lanes (block-sum adds all lanes)
    {
      float F2 = (g == 0) ? F2a : F2b;
      float n2d = (g == 0) ? n2a : n2b;
      float w2t = (g == 0) ? w2ta : w2tb;
      float p2g = (g == 0) ? p2ga : p2gb;
      float det = (g == 0) ? det0 : det1;
      float lpo = (g == 0) ? lp0 : lp1;
      if (g < 2) {
        float n2 = n2d + 2.0f*w2t + c2v;
        float v  = sqrtf(fabsf(det) + 1e-10f);
        float nn = sqrtf(fmaxf(n2, 0.0f));
        float rr = fmaf(v, nn, 1e-8f);
        float a2 = 7.0f * v * v / (rr * rr);
        float be = v / (rr * nn + 1e-20f);
        float fac = be * (2.0f - be * n2);
        float dual = a2 * (F2 - fac * p2g);
        float dm1 = det - 1.0f, nm7 = n2 - 7.0f;
        acc += F2 + dual + dm1*dm1 + nm7*nm7 + lpo;
      }
    }
  }

  // ---- block reduction (clobbers weight LDS; all waves done) ----
  __syncthreads();
  float* SFw = (float*)SMEM;
  SFw[tid] = acc;
  __syncthreads();
  #pragma unroll
  for (int s = 256; s > 0; s >>= 1) {
    if (tid < s) SFw[tid] += SFw[tid + s];
    __syncthreads();
  }
  if (tid == 0) partials[blockIdx.x] = SFw[0];
}

__global__ void g2_finish(const float* __restrict__ partials, float* __restrict__ out) {
  __shared__ float red[256];
  int t = threadIdx.x;
  red[t] = partials[t] + partials[t + 256];
  __syncthreads();
  #pragma unroll
  for (int s = 128; s > 0; s >>= 1) {
    if (t < s) red[t] += red[t + s];
    __syncthreads();
  }
  if (t == 0) out[0] = red[0] * (1.0f / (float)B_TOTAL);
}

extern "C" void kernel_launch(void* const* d_in, const int* in_sizes, int n_in,
                              void* d_out, int out_size, void* d_ws, size_t ws_size,
                              hipStream_t stream) {
  (void)in_sizes; (void)n_in; (void)out_size; (void)ws_size;
  const float* coords = (const float*)d_in[0];
  const float* metric = (const float*)d_in[1];
  const float* W1     = (const float*)d_in[2];
  const float* b1     = (const float*)d_in[3];
  const float* W2     = (const float*)d_in[4];
  const float* b2     = (const float*)d_in[5];
  float* out = (float*)d_out;

  u32* ws = (u32*)d_ws;
  float* partials = (float*)(ws + NW_U32);

  g2_prep<<<41, 256, 0, stream>>>(W1, b1, W2, b2, ws);
  g2_main<<<NBLK, 512, 0, stream>>>(coords, metric, ws, partials);
  g2_finish<<<1, 256, 0, stream>>>(partials, out);
}